// Round 1
// baseline (646.078 us; speedup 1.0000x reference)
//
#include <hip/hip_runtime.h>

// Graphormer layer, MI355X round 1.
// N=4096, D=512, H=8, DH=64, F=2048. fp32 in/out, bf16 MFMA internally.

typedef float f32x4 __attribute__((ext_vector_type(4)));
typedef short s8v  __attribute__((ext_vector_type(8)));   // 8 bf16 in 4 VGPRs
typedef unsigned short u16;

#define MFMA16(a,b,c) __builtin_amdgcn_mfma_f32_16x16x32_bf16((a),(b),(c),0,0,0)

static constexpr int N  = 4096;
static constexpr int D  = 512;
static constexpr int H  = 8;
static constexpr int DH = 64;
static constexpr int F  = 2048;
static constexpr int QKVW = 3 * D;       // 1536
static constexpr int NH   = N * H;       // 32768 (bias row stride in floats)

__device__ inline u16 f2bf(float f) {
  union { float f; unsigned u; } x; x.f = f;
  unsigned r = x.u + 0x7fffu + ((x.u >> 16) & 1u);
  return (u16)(r >> 16);
}

// ---------------- LayerNorm: fp32 (N,512) -> bf16 (N,512) ----------------
__global__ __launch_bounds__(256) void ln_kernel(const float* __restrict__ x,
                                                 const float* __restrict__ g,
                                                 const float* __restrict__ b,
                                                 u16* __restrict__ out) {
  const int row  = blockIdx.x * 4 + (threadIdx.x >> 6);
  const int lane = threadIdx.x & 63;
  const float4* xr = (const float4*)(x + (size_t)row * D);
  float4 v0 = xr[lane], v1 = xr[64 + lane];
  float s  = v0.x + v0.y + v0.z + v0.w + v1.x + v1.y + v1.z + v1.w;
  float ss = v0.x*v0.x + v0.y*v0.y + v0.z*v0.z + v0.w*v0.w
           + v1.x*v1.x + v1.y*v1.y + v1.z*v1.z + v1.w*v1.w;
  for (int off = 1; off < 64; off <<= 1) {
    s  += __shfl_xor(s,  off);
    ss += __shfl_xor(ss, off);
  }
  const float mu   = s * (1.0f / D);
  const float var  = ss * (1.0f / D) - mu * mu;
  const float rstd = rsqrtf(var + 1e-5f);
  const float4* g4 = (const float4*)g;
  const float4* b4 = (const float4*)b;
  float4 g0 = g4[lane], g1 = g4[64 + lane];
  float4 b0 = b4[lane], b1 = b4[64 + lane];
  u16* orow = out + (size_t)row * D;
  ushort4 o0, o1;
  o0.x = f2bf((v0.x - mu) * rstd * g0.x + b0.x);
  o0.y = f2bf((v0.y - mu) * rstd * g0.y + b0.y);
  o0.z = f2bf((v0.z - mu) * rstd * g0.z + b0.z);
  o0.w = f2bf((v0.w - mu) * rstd * g0.w + b0.w);
  o1.x = f2bf((v1.x - mu) * rstd * g1.x + b1.x);
  o1.y = f2bf((v1.y - mu) * rstd * g1.y + b1.y);
  o1.z = f2bf((v1.z - mu) * rstd * g1.z + b1.z);
  o1.w = f2bf((v1.w - mu) * rstd * g1.w + b1.w);
  ((ushort4*)orow)[lane]      = o0;
  ((ushort4*)orow)[64 + lane] = o1;
}

// ------------- weight transpose fp32 (R,C) -> bf16 (C,R) ----------------
__global__ void transpose_w(const float* __restrict__ src, u16* __restrict__ dst,
                            int R, int C) {
  int idx = blockIdx.x * 256 + threadIdx.x;
  if (idx < R * C) {
    int r = idx / C, c = idx - r * C;
    dst[(size_t)c * R + r] = f2bf(src[idx]);
  }
}

__global__ void pack_bqkv(const float* __restrict__ bq, const float* __restrict__ bk,
                          const float* __restrict__ bv, float* __restrict__ bqkv) {
  int i = blockIdx.x * 256 + threadIdx.x;
  if (i < QKVW) bqkv[i] = (i < D) ? bq[i] : (i < 2 * D) ? bk[i - D] : bv[i - 2 * D];
}

// -------- V transpose: qkv (N,1536) cols 1024.. -> vT (H*DH, N) bf16 -----
__global__ void transpose_v(const u16* __restrict__ qkv, u16* __restrict__ vT) {
  int idx = blockIdx.x * 256 + threadIdx.x;       // over 512*4096
  int n  = idx & (N - 1);
  int hd = idx >> 12;                              // h*64+dh
  vT[idx] = qkv[(size_t)n * QKVW + 2 * D + hd];
}

// -------------------- GEMM: C = A @ Bt^T (+epilogue) ---------------------
// A: (M,K) bf16 row-major; Bt: (Nn,K) bf16 row-major (pre-transposed B).
// MODE 0: out bf16 = acc+bias; 1: out bf16 = gelu(acc+bias);
// MODE 2: out f32 = acc+bias+res.
template <int MODE>
__global__ __launch_bounds__(256) void gemm_bt(const u16* __restrict__ A,
                                               const u16* __restrict__ Bt,
                                               const float* __restrict__ bias,
                                               const float* __restrict__ res,
                                               void* __restrict__ outv,
                                               int M, int Nn, int K) {
  __shared__ __align__(16) u16 As[128 * 32];
  __shared__ __align__(16) u16 Bs[128 * 32];
  const int t = threadIdx.x;
  const int lane = t & 63, w = t >> 6;
  const int wr = w >> 1, wc = w & 1;
  const int lr = lane & 15, lq = lane >> 4;
  const int r0 = blockIdx.y * 128, c0 = blockIdx.x * 128;
  const int rr = t >> 2, cc = (t & 3) * 8;
  f32x4 acc[4][4] = {};
  for (int k0 = 0; k0 < K; k0 += 32) {
    __syncthreads();
    *(s8v*)&As[rr * 32 + cc]        = *(const s8v*)&A[(size_t)(r0 + rr) * K + k0 + cc];
    *(s8v*)&As[(64 + rr) * 32 + cc] = *(const s8v*)&A[(size_t)(r0 + 64 + rr) * K + k0 + cc];
    *(s8v*)&Bs[rr * 32 + cc]        = *(const s8v*)&Bt[(size_t)(c0 + rr) * K + k0 + cc];
    *(s8v*)&Bs[(64 + rr) * 32 + cc] = *(const s8v*)&Bt[(size_t)(c0 + 64 + rr) * K + k0 + cc];
    __syncthreads();
    s8v af[4], bf[4];
#pragma unroll
    for (int m = 0; m < 4; m++) af[m] = *(const s8v*)&As[(wr * 64 + m * 16 + lr) * 32 + lq * 8];
#pragma unroll
    for (int n = 0; n < 4; n++) bf[n] = *(const s8v*)&Bs[(wc * 64 + n * 16 + lr) * 32 + lq * 8];
#pragma unroll
    for (int m = 0; m < 4; m++)
#pragma unroll
      for (int n = 0; n < 4; n++) acc[m][n] = MFMA16(af[m], bf[n], acc[m][n]);
  }
#pragma unroll
  for (int m = 0; m < 4; m++)
#pragma unroll
    for (int n = 0; n < 4; n++) {
      const int col = c0 + wc * 64 + n * 16 + lr;
      const float bcol = bias[col];
#pragma unroll
      for (int j = 0; j < 4; j++) {
        const int row = r0 + wr * 64 + m * 16 + lq * 4 + j;
        float v = acc[m][n][j] + bcol;
        if (MODE == 0) {
          ((u16*)outv)[(size_t)row * Nn + col] = f2bf(v);
        } else if (MODE == 1) {
          v = 0.5f * v * (1.0f + erff(v * 0.70710678118654752f));
          ((u16*)outv)[(size_t)row * Nn + col] = f2bf(v);
        } else {
          ((float*)outv)[(size_t)row * Nn + col] = v + res[(size_t)row * Nn + col];
        }
      }
    }
}

// ----------------------- flash attention + bias --------------------------
// grid: N/16 blocks; block: 512 threads = 8 waves; wave h handles head h.
// Per wave: 16 q-rows, iterate m in tiles of 64 with online softmax.
__global__ __launch_bounds__(512) void attn_kernel(const u16* __restrict__ qkv,
                                                   const u16* __restrict__ vT,
                                                   const float* __restrict__ bias,
                                                   u16* __restrict__ ctx) {
  __shared__ __align__(16) u16 P_lds[8][16 * 64];
  const int lane = threadIdx.x & 63, h = threadIdx.x >> 6;
  const int lr = lane & 15, lq = lane >> 4;
  const int q0 = blockIdx.x * 16;

  const u16* qp = qkv + (size_t)(q0 + lr) * QKVW + h * DH + lq * 8;
  s8v qf0 = *(const s8v*)qp;
  s8v qf1 = *(const s8v*)(qp + 32);

  f32x4 cacc[4] = {};
  float mrun[4], lrun[4];
#pragma unroll
  for (int j = 0; j < 4; j++) { mrun[j] = -1e30f; lrun[j] = 0.0f; }
  u16* pl = P_lds[h];

  for (int m0 = 0; m0 < N; m0 += 64) {
    // ---- S = Q K^T (per-head): 16 x 64 tile ----
    f32x4 sacc[4] = {};
    const u16* kp = qkv + (size_t)(m0 + lr) * QKVW + D + h * DH + lq * 8;
#pragma unroll
    for (int nb = 0; nb < 4; nb++) {
      s8v k0v = *(const s8v*)(kp + (size_t)nb * 16 * QKVW);
      s8v k1v = *(const s8v*)(kp + (size_t)nb * 16 * QKVW + 32);
      sacc[nb] = MFMA16(qf0, k0v, sacc[nb]);
      sacc[nb] = MFMA16(qf1, k1v, sacc[nb]);
    }
    // ---- scale + bias; track tile row-max ----
    float p[4][4];
    float tmax[4] = {-1e30f, -1e30f, -1e30f, -1e30f};
#pragma unroll
    for (int nb = 0; nb < 4; nb++) {
      const float* bp = bias + (size_t)(q0 + lq * 4) * NH + (size_t)(m0 + nb * 16 + lr) * H + h;
#pragma unroll
      for (int j = 0; j < 4; j++) {
        float sv = sacc[nb][j] * 0.125f + bp[(size_t)j * NH];
        p[nb][j] = sv;
        tmax[j] = fmaxf(tmax[j], sv);
      }
    }
#pragma unroll
    for (int j = 0; j < 4; j++) {
      tmax[j] = fmaxf(tmax[j], __shfl_xor(tmax[j], 1));
      tmax[j] = fmaxf(tmax[j], __shfl_xor(tmax[j], 2));
      tmax[j] = fmaxf(tmax[j], __shfl_xor(tmax[j], 4));
      tmax[j] = fmaxf(tmax[j], __shfl_xor(tmax[j], 8));
    }
    float scale[4];
#pragma unroll
    for (int j = 0; j < 4; j++) {
      float mnew = fmaxf(mrun[j], tmax[j]);
      scale[j] = __expf(mrun[j] - mnew);
      mrun[j] = mnew;
    }
#pragma unroll
    for (int nb = 0; nb < 4; nb++)
#pragma unroll
      for (int j = 0; j < 4; j++) p[nb][j] = __expf(p[nb][j] - mrun[j]);
#pragma unroll
    for (int j = 0; j < 4; j++) {
      float rs = p[0][j] + p[1][j] + p[2][j] + p[3][j];
      rs += __shfl_xor(rs, 1);
      rs += __shfl_xor(rs, 2);
      rs += __shfl_xor(rs, 4);
      rs += __shfl_xor(rs, 8);
      lrun[j] = lrun[j] * scale[j] + rs;
    }
#pragma unroll
    for (int nbd = 0; nbd < 4; nbd++)
#pragma unroll
      for (int j = 0; j < 4; j++) cacc[nbd][j] *= scale[j];
    // ---- P -> LDS (D-layout) ; read back as A-operand layout ----
#pragma unroll
    for (int nb = 0; nb < 4; nb++)
#pragma unroll
      for (int j = 0; j < 4; j++)
        pl[(lq * 4 + j) * 64 + nb * 16 + lr] = f2bf(p[nb][j]);
    s8v pf0 = *(const s8v*)&pl[lr * 64 + lq * 8];
    s8v pf1 = *(const s8v*)&pl[lr * 64 + 32 + lq * 8];
    // ---- ctx += P @ V ----
    const u16* vp = vT + (size_t)(h * DH + lr) * N + m0 + lq * 8;
#pragma unroll
    for (int nbd = 0; nbd < 4; nbd++) {
      s8v v0 = *(const s8v*)(vp + (size_t)nbd * 16 * N);
      s8v v1 = *(const s8v*)(vp + (size_t)nbd * 16 * N + 32);
      cacc[nbd] = MFMA16(pf0, v0, cacc[nbd]);
      cacc[nbd] = MFMA16(pf1, v1, cacc[nbd]);
    }
  }
  // ---- normalize + write ctx (N,512) bf16 ----
#pragma unroll
  for (int nbd = 0; nbd < 4; nbd++)
#pragma unroll
    for (int j = 0; j < 4; j++) {
      float v = cacc[nbd][j] / lrun[j];
      ctx[(size_t)(q0 + lq * 4 + j) * D + h * DH + nbd * 16 + lr] = f2bf(v);
    }
}

// ------------------------------- launch ----------------------------------
extern "C" void kernel_launch(void* const* d_in, const int* in_sizes, int n_in,
                              void* d_out, int out_size, void* d_ws, size_t ws_size,
                              hipStream_t stream) {
  const float* x    = (const float*)d_in[0];
  const float* abias= (const float*)d_in[1];
  const float* ln1g = (const float*)d_in[2];
  const float* ln1b = (const float*)d_in[3];
  const float* wq   = (const float*)d_in[4];
  const float* bq   = (const float*)d_in[5];
  const float* wk   = (const float*)d_in[6];
  const float* bk   = (const float*)d_in[7];
  const float* wv   = (const float*)d_in[8];
  const float* bv   = (const float*)d_in[9];
  const float* wo   = (const float*)d_in[10];
  const float* bo   = (const float*)d_in[11];
  const float* ln2g = (const float*)d_in[12];
  const float* ln2b = (const float*)d_in[13];
  const float* w1   = (const float*)d_in[14];
  const float* b1   = (const float*)d_in[15];
  const float* w2   = (const float*)d_in[16];
  const float* b2   = (const float*)d_in[17];
  float* out = (float*)d_out;

  char* ws = (char*)d_ws;
  size_t off = 0;
  auto alloc = [&](size_t bytes) { size_t o = off; off = (off + bytes + 255) & ~(size_t)255; return (void*)(ws + o); };
  u16*   xn    = (u16*)alloc((size_t)N * D * 2);
  u16*   qkv   = (u16*)alloc((size_t)N * QKVW * 2);
  u16*   vT    = (u16*)alloc((size_t)D * N * 2);
  u16*   ctx   = (u16*)alloc((size_t)N * D * 2);
  float* x2    = (float*)alloc((size_t)N * D * 4);
  u16*   xn2   = (u16*)alloc((size_t)N * D * 2);
  u16*   hb    = (u16*)alloc((size_t)N * F * 2);
  u16*   WqkvT = (u16*)alloc((size_t)QKVW * D * 2);
  u16*   WoT   = (u16*)alloc((size_t)D * D * 2);
  u16*   W1T   = (u16*)alloc((size_t)F * D * 2);
  u16*   W2T   = (u16*)alloc((size_t)D * F * 2);
  float* bqkv  = (float*)alloc((size_t)QKVW * 4);

  // weight prep (every call: deterministic)
  transpose_w<<<(D * D + 255) / 256, 256, 0, stream>>>(wq, WqkvT, D, D);
  transpose_w<<<(D * D + 255) / 256, 256, 0, stream>>>(wk, WqkvT + D * D, D, D);
  transpose_w<<<(D * D + 255) / 256, 256, 0, stream>>>(wv, WqkvT + 2 * D * D, D, D);
  transpose_w<<<(D * D + 255) / 256, 256, 0, stream>>>(wo, WoT, D, D);
  transpose_w<<<(D * F + 255) / 256, 256, 0, stream>>>(w1, W1T, D, F);
  transpose_w<<<(F * D + 255) / 256, 256, 0, stream>>>(w2, W2T, F, D);
  pack_bqkv<<<(QKVW + 255) / 256, 256, 0, stream>>>(bq, bk, bv, bqkv);

  // LN1
  ln_kernel<<<N / 4, 256, 0, stream>>>(x, ln1g, ln1b, xn);
  // QKV
  gemm_bt<0><<<dim3(QKVW / 128, N / 128), 256, 0, stream>>>(xn, WqkvT, bqkv, nullptr, qkv, N, QKVW, D);
  // V transpose
  transpose_v<<<(D * N) / 256, 256, 0, stream>>>(qkv, vT);
  // attention
  attn_kernel<<<N / 16, 512, 0, stream>>>(qkv, vT, abias, ctx);
  // O proj + residual -> x2 (fp32)
  gemm_bt<2><<<dim3(D / 128, N / 128), 256, 0, stream>>>(ctx, WoT, bo, x, x2, N, D, D);
  // LN2
  ln_kernel<<<N / 4, 256, 0, stream>>>(x2, ln2g, ln2b, xn2);
  // FFN1 + gelu
  gemm_bt<1><<<dim3(F / 128, N / 128), 256, 0, stream>>>(xn2, W1T, b1, nullptr, hb, N, F, D);
  // FFN2 + residual -> out (fp32)
  gemm_bt<2><<<dim3(D / 128, N / 128), 256, 0, stream>>>(hb, W2T, b2, x2, out, N, D, F);
  (void)in_sizes; (void)n_in; (void)out_size; (void)ws_size;
}